// Round 3
// baseline (1524.723 us; speedup 1.0000x reference)
//
#include <hip/hip_runtime.h>
#include <hip/hip_bf16.h>
#include <stdint.h>

// Problem constants: H=2048, I=4096, E=8, TOPK=2, B*S=4096
#define H_DIM 2048
#define I_DIM 4096
#define NEXP  8
#define NTOK  4096
#define NPAIR 8192
#define PAD_ROWS (NPAIR + 256)

// Workspace layout (bytes)
#define MiB (1024ull * 1024ull)
#define WS_COUNTS   0ull
#define WS_OFFSETS  256ull
#define WS_TOKID    1024ull
#define WS_SLOT     (64ull * 1024)
#define WS_PAIRW    (128ull * 1024)
#define WS_XG       (1ull * MiB)
#define WS_INTER    (36ull * MiB)
#define WS_Y        (104ull * MiB)
#define WS_GW       (176ull * MiB)
#define WS_UW       (304ull * MiB)
#define WS_DW       (432ull * MiB)
#define WS_FULL     (560ull * MiB)

typedef __attribute__((ext_vector_type(8))) short bf16x8;
typedef __attribute__((ext_vector_type(4))) float f32x4;

#if defined(__has_builtin)
#if __has_builtin(__builtin_amdgcn_cvt_pk_bf16_f32)
#define HAVE_CVT_PK 1
#endif
#endif

__device__ __forceinline__ uint32_t bf16_bits_rne(float x) {
  uint32_t u = __float_as_uint(x);
  return (u + 0x7FFFu + ((u >> 16) & 1u)) >> 16;
}
__device__ __forceinline__ uint32_t pk_bf16(float a, float b) {
#ifdef HAVE_CVT_PK
  auto r = __builtin_amdgcn_cvt_pk_bf16_f32(a, b);
  return __builtin_bit_cast(uint32_t, r);
#else
  return bf16_bits_rne(a) | (bf16_bits_rne(b) << 16);
#endif
}
__device__ __forceinline__ uint16_t bf16_one(float x) {
  return (uint16_t)(pk_bf16(x, x) & 0xFFFFu);
}

// async global->LDS, 16B/lane: lane i lands at lds_base + 16*i (base wave-uniform)
__device__ __forceinline__ void async_load16(const void* g, void* l) {
  __builtin_amdgcn_global_load_lds(
      (const __attribute__((address_space(1))) void*)g,
      (__attribute__((address_space(3))) void*)l, 16, 0, 0);
}

#define WAIT_VM8()  do { asm volatile("s_waitcnt vmcnt(8)" ::: "memory"); __builtin_amdgcn_sched_barrier(0); } while (0)
#define WAIT_VM6()  do { asm volatile("s_waitcnt vmcnt(6)" ::: "memory"); __builtin_amdgcn_sched_barrier(0); } while (0)
#define WAIT_VM0()  do { asm volatile("s_waitcnt vmcnt(0)" ::: "memory"); __builtin_amdgcn_sched_barrier(0); } while (0)
#define BARRIER()   do { __builtin_amdgcn_s_barrier(); asm volatile("" ::: "memory"); } while (0)

// ---------------- routing ----------------
__global__ void route_kernel(const int* __restrict__ idx, const float* __restrict__ wts,
                             int* __restrict__ ws_counts, int* __restrict__ ws_offsets,
                             int* __restrict__ tokid, int* __restrict__ slotOf,
                             float* __restrict__ pairw) {
  __shared__ int s_cnt[NEXP], s_off[NEXP], s_cur[NEXP];
  int tid = threadIdx.x;
  if (tid < NEXP) s_cnt[tid] = 0;
  __syncthreads();
  for (int p = tid; p < NPAIR; p += 256) atomicAdd(&s_cnt[idx[p]], 1);
  __syncthreads();
  if (tid == 0) {
    int acc = 0;
    for (int e = 0; e < NEXP; e++) { s_off[e] = acc; s_cur[e] = acc; acc += s_cnt[e]; }
  }
  __syncthreads();
  for (int p = tid; p < NPAIR; p += 256) {
    int e = idx[p];
    int slot = atomicAdd(&s_cur[e], 1);
    tokid[slot] = p >> 1;
    slotOf[p] = slot;
    pairw[slot] = wts[p];
  }
  if (tid < NEXP) { ws_counts[tid] = s_cnt[tid]; ws_offsets[tid] = s_off[tid]; }
}

// ---------------- gather routed rows of x, fp32 -> bf16 ----------------
__global__ void gather_cast_kernel(const float* __restrict__ x, const int* __restrict__ tokid,
                                   uint16_t* __restrict__ xg) {
  int p = blockIdx.x;
  int t = tokid[p];
  int c = threadIdx.x * 8;
  const float4* src = (const float4*)(x + (size_t)t * H_DIM + c);
  float4 v0 = src[0], v1 = src[1];
  uint4 o;
  o.x = pk_bf16(v0.x, v0.y); o.y = pk_bf16(v0.z, v0.w);
  o.z = pk_bf16(v1.x, v1.y); o.w = pk_bf16(v1.z, v1.w);
  *(uint4*)(xg + (size_t)p * H_DIM + c) = o;
}

// ---------------- one-shot weight cast fp32 -> bf16 ----------------
__global__ void cast3_kernel(const float* __restrict__ g, const float* __restrict__ u,
                             const float* __restrict__ d,
                             uint16_t* __restrict__ gw, uint16_t* __restrict__ uw,
                             uint16_t* __restrict__ dw) {
  const float* src = blockIdx.y == 0 ? g : (blockIdx.y == 1 ? u : d);
  uint16_t*    dst = blockIdx.y == 0 ? gw : (blockIdx.y == 1 ? uw : dw);
  const long long n8 = (long long)NEXP * I_DIM * H_DIM / 8;
  long long stride = (long long)gridDim.x * blockDim.x;
  for (long long i = (long long)blockIdx.x * blockDim.x + threadIdx.x; i < n8; i += stride) {
    const float4* s = (const float4*)(src + i * 8);
    float4 a = s[0], b = s[1];
    uint4 o = { pk_bf16(a.x, a.y), pk_bf16(a.z, a.w), pk_bf16(b.x, b.y), pk_bf16(b.z, b.w) };
    *(uint4*)(dst + i * 8) = o;
  }
}

// =====================================================================================
// GEMM1 v3: 4-phase-per-K-tile (m201-style). Tile 256 rows x 256 n-cols (128 gate +
// 128 up interleaved 32-per-wave), BK=64, 8 waves (2M x 4N), wave tile 128x64.
// LDS [2 dbuf][2 khalf][256 rows][32 k] for A and B (128 KB). khalf-major layout is
// bank-conflict-free for the MFMA frag reads. Stage slots: P1/P2 -> (t+1)-kh1,
// P3/P4 -> (t+2)-kh0; vmcnt(8) before trailing barrier of P2/P4 (vmcnt(0) in tail).
// =====================================================================================
#define NT1 (H_DIM / 64)   // 32

__global__ __launch_bounds__(512, 2)
void gemm1_v3(const uint16_t* __restrict__ xg,
              const uint16_t* __restrict__ gw, const uint16_t* __restrict__ uw,
              const int* __restrict__ ws_counts, const int* __restrict__ ws_offsets,
              uint16_t* __restrict__ inter) {
  int e = blockIdx.z;
  int cnt = ws_counts[e];
  int rowTile = blockIdx.y;
  if (rowTile * 256 >= cnt) return;
  int off = ws_offsets[e];
  int colBase = blockIdx.x * 128;          // gate-col base (block covers 128 gate + 128 up)
  size_t rowBase = (size_t)off + (size_t)rowTile * 256;

  __shared__ uint16_t sA[2][2][256][32];   // 64 KB
  __shared__ uint16_t sB[2][2][256][32];   // 64 KB, n-rows: per wave-64 [32 gate | 32 up]

  int tid = threadIdx.x, lane = tid & 63, w = tid >> 6;
  int lcol = lane & 15, quad = lane >> 4;
  int wr = w >> 2, wc = w & 3;             // 2M x 4N

  // per-lane stage sources (c = 0,1): 16 rows per wave-inst, 64B per row slice
  int lr = lane >> 2, lk = (lane & 3) * 8;
  const uint16_t* aSrc[2];
  const uint16_t* bSrc[2];
#pragma unroll
  for (int c = 0; c < 2; c++) {
    int ar = (w * 2 + c) * 16 + lr;
    aSrc[c] = xg + (rowBase + ar) * H_DIM + lk;
    int jn = ar;                           // B n-row
    int jw = jn >> 6, v = jn & 63;
    const uint16_t* wbase = (v < 32) ? gw : uw;
    bSrc[c] = wbase + ((size_t)e * I_DIM + colBase + jw * 32 + (v & 31)) * H_DIM + lk;
  }

  f32x4 acc[8][4];
  f32x4 zero = {0.f, 0.f, 0.f, 0.f};
#pragma unroll
  for (int mf = 0; mf < 8; mf++)
#pragma unroll
    for (int ni = 0; ni < 4; ni++) acc[mf][ni] = zero;

  auto STG_A = [&](int buf, int kh, int kt) {
    int ko = kt * 64 + kh * 32;
    async_load16(aSrc[0] + ko, &sA[buf][kh][(w * 2 + 0) * 16][0]);
    async_load16(aSrc[1] + ko, &sA[buf][kh][(w * 2 + 1) * 16][0]);
  };
  auto STG_B = [&](int buf, int kh, int kt) {
    int ko = kt * 64 + kh * 32;
    async_load16(bSrc[0] + ko, &sB[buf][kh][(w * 2 + 0) * 16][0]);
    async_load16(bSrc[1] + ko, &sB[buf][kh][(w * 2 + 1) * 16][0]);
  };

#define RD1(KS, MQ)                                                                   \
  _Pragma("unroll") for (int mi = 0; mi < 4; mi++)                                    \
    af[mi] = *(const bf16x8*)&sA[b][KS][wr * 128 + MQ * 64 + mi * 16 + lcol][quad * 8]; \
  _Pragma("unroll") for (int ni = 0; ni < 4; ni++)                                    \
    bb[ni] = *(const bf16x8*)&sB[b][KS][wc * 64 + ni * 16 + lcol][quad * 8];

#define MM1(MQ)                                                                       \
  __builtin_amdgcn_s_setprio(1);                                                      \
  _Pragma("unroll") for (int mi = 0; mi < 4; mi++)                                    \
    _Pragma("unroll") for (int ni = 0; ni < 4; ni++)                                  \
      acc[MQ * 4 + mi][ni] = __builtin_amdgcn_mfma_f32_16x16x32_bf16(                 \
          af[mi], bb[ni], acc[MQ * 4 + mi][ni], 0, 0, 0);                             \
  __builtin_amdgcn_s_setprio(0);

  // prologue: t0-kh0, t0-kh1, t1-kh0 (12 loads); retire t0-kh0
  STG_A(0, 0, 0); STG_B(0, 0, 0);
  STG_A(0, 1, 0); STG_B(0, 1, 0);
  STG_A(1, 0, 1); STG_B(1, 0, 1);
  WAIT_VM8();
  BARRIER();

  for (int t = 0; t < NT1; ++t) {
    const int b = t & 1, bn = b ^ 1;
    const bool tail = (t >= NT1 - 2);
    bf16x8 af[4], bb[4];
    // P1 (ks0, mq0): stage A-kh1(t+1)
    RD1(0, 0);
    if (t + 1 < NT1) STG_A(bn, 1, t + 1);
    BARRIER();
    MM1(0);
    BARRIER();
    // P2 (ks0, mq1): stage B-kh1(t+1); gate kh1 of t
    RD1(0, 1);
    if (t + 1 < NT1) STG_B(bn, 1, t + 1);
    BARRIER();
    MM1(1);
    if (tail) { WAIT_VM0(); } else { WAIT_VM8(); }
    BARRIER();
    // P3 (ks1, mq0): stage A-kh0(t+2)
    RD1(1, 0);
    if (t + 2 < NT1) STG_A(b, 0, t + 2);
    BARRIER();
    MM1(0);
    BARRIER();
    // P4 (ks1, mq1): stage B-kh0(t+2); gate kh0 of t+1
    RD1(1, 1);
    if (t + 2 < NT1) STG_B(b, 0, t + 2);
    BARRIER();
    MM1(1);
    if (tail) { WAIT_VM0(); } else { WAIT_VM8(); }
    BARRIER();
  }
#undef RD1
#undef MM1

  // epilogue: silu(g)*u -> bf16 inter. C frag: col=lane&15, row=quad*4+r
#pragma unroll
  for (int mq = 0; mq < 2; mq++) {
#pragma unroll
    for (int mi = 0; mi < 4; mi++) {
#pragma unroll
      for (int r = 0; r < 4; r++) {
        int localRow = rowTile * 256 + wr * 128 + mq * 64 + mi * 16 + quad * 4 + r;
        if (localRow < cnt) {
          size_t prow = (size_t)off + localRow;
#pragma unroll
          for (int ni = 0; ni < 2; ni++) {
            float g = acc[mq * 4 + mi][ni][r];
            float u = acc[mq * 4 + mi][ni + 2][r];
            float v = (g / (1.f + __expf(-g))) * u;
            inter[prow * I_DIM + colBase + wc * 32 + ni * 16 + lcol] = bf16_one(v);
          }
        }
      }
    }
  }
}

// =====================================================================================
// GEMM2 v3: same schedule, 2 phases per K-tile. Tile 256 rows x 128 cols, BK=64,
// 8 waves (4M x 2N), wave tile 64x64. LDS: A 64 KB + B 32 KB = 96 KB.
// Stage slots: P1 -> (t+1)-kh1, P2 -> (t+2)-kh0; vmcnt(6) per phase end.
// =====================================================================================
#define NT2 (I_DIM / 64)   // 64

__global__ __launch_bounds__(512, 2)
void gemm2_v3(const uint16_t* __restrict__ inter, const uint16_t* __restrict__ dw,
              const int* __restrict__ ws_counts, const int* __restrict__ ws_offsets,
              const float* __restrict__ pairw, float* __restrict__ y) {
  int e = blockIdx.z;
  int cnt = ws_counts[e];
  int rowTile = blockIdx.y;
  if (rowTile * 256 >= cnt) return;
  int off = ws_offsets[e];
  int colBase = blockIdx.x * 128;
  size_t rowBase = (size_t)off + (size_t)rowTile * 256;

  __shared__ uint16_t sA[2][2][256][32];   // 64 KB
  __shared__ uint16_t sB[2][2][128][32];   // 32 KB

  int tid = threadIdx.x, lane = tid & 63, w = tid >> 6;
  int lcol = lane & 15, quad = lane >> 4;
  int wr = w >> 1, wc = w & 1;             // 4M x 2N

  int lr = lane >> 2, lk = (lane & 3) * 8;
  const uint16_t* aSrc[2];
#pragma unroll
  for (int c = 0; c < 2; c++) {
    int ar = (w * 2 + c) * 16 + lr;
    aSrc[c] = inter + (rowBase + ar) * I_DIM + lk;
  }
  const uint16_t* bSrc = dw + ((size_t)e * H_DIM + colBase + w * 16 + lr) * I_DIM + lk;

  f32x4 acc[4][4];
  f32x4 zero = {0.f, 0.f, 0.f, 0.f};
#pragma unroll
  for (int mi = 0; mi < 4; mi++)
#pragma unroll
    for (int ni = 0; ni < 4; ni++) acc[mi][ni] = zero;

  auto STG_A = [&](int buf, int kh, int kt) {
    int ko = kt * 64 + kh * 32;
    async_load16(aSrc[0] + ko, &sA[buf][kh][(w * 2 + 0) * 16][0]);
    async_load16(aSrc[1] + ko, &sA[buf][kh][(w * 2 + 1) * 16][0]);
  };
  auto STG_B = [&](int buf, int kh, int kt) {
    int ko = kt * 64 + kh * 32;
    async_load16(bSrc + ko, &sB[buf][kh][w * 16][0]);
  };

#define RD2(KS)                                                                       \
  _Pragma("unroll") for (int mi = 0; mi < 4; mi++)                                    \
    af[mi] = *(const bf16x8*)&sA[b][KS][wr * 64 + mi * 16 + lcol][quad * 8];          \
  _Pragma("unroll") for (int ni = 0; ni < 4; ni++)                                    \
    bb[ni] = *(const bf16x8*)&sB[b][KS][wc * 64 + ni * 16 + lcol][quad * 8];

#define MM2()                                                                         \
  __builtin_amdgcn_s_setprio(1);                                                      \
  _Pragma("unroll") for (int mi = 0; mi < 4; mi++)                                    \
    _Pragma("unroll") for (int ni = 0; ni < 4; ni++)                                  \
      acc[mi][ni] = __builtin_amdgcn_mfma_f32_16x16x32_bf16(                          \
          af[mi], bb[ni], acc[mi][ni], 0, 0, 0);                                      \
  __builtin_amdgcn_s_setprio(0);

  // prologue: t0-kh0, t0-kh1, t1-kh0 (9 loads); retire t0-kh0
  STG_A(0, 0, 0); STG_B(0, 0, 0);
  STG_A(0, 1, 0); STG_B(0, 1, 0);
  STG_A(1, 0, 1); STG_B(1, 0, 1);
  WAIT_VM6();
  BARRIER();

  for (int t = 0; t < NT2; ++t) {
    const int b = t & 1, bn = b ^ 1;
    const bool tail = (t >= NT2 - 2);
    bf16x8 af[4], bb[4];
    // P1 (ks0): stage (t+1)-kh1; gate kh1 of t
    RD2(0);
    if (t + 1 < NT2) { STG_A(bn, 1, t + 1); STG_B(bn, 1, t + 1); }
    BARRIER();
    MM2();
    if (tail) { WAIT_VM0(); } else { WAIT_VM6(); }
    BARRIER();
    // P2 (ks1): stage (t+2)-kh0; gate kh0 of t+1
    RD2(1);
    if (t + 2 < NT2) { STG_A(b, 0, t + 2); STG_B(b, 0, t + 2); }
    BARRIER();
    MM2();
    if (tail) { WAIT_VM0(); } else { WAIT_VM6(); }
    BARRIER();
  }
#undef RD2
#undef MM2

#pragma unroll
  for (int mi = 0; mi < 4; mi++) {
#pragma unroll
    for (int r = 0; r < 4; r++) {
      int localRow = rowTile * 256 + wr * 64 + mi * 16 + quad * 4 + r;
      if (localRow < cnt) {
        size_t prow = (size_t)off + localRow;
        float wgt = pairw[prow];
        float* yr = y + prow * H_DIM + colBase + wc * 64;
#pragma unroll
        for (int ni = 0; ni < 4; ni++)
          yr[ni * 16 + lcol] = acc[mi][ni][r] * wgt;
      }
    }
  }
}

// ---------------- combine: out[t] = y[slot(2t)] + y[slot(2t+1)] ----------------
__global__ void combine_kernel(const float* __restrict__ y, const int* __restrict__ slotOf,
                               float* __restrict__ out) {
  int t = blockIdx.x;
  int s0 = slotOf[2 * t], s1 = slotOf[2 * t + 1];
  int c = threadIdx.x * 8;
  const float4* a = (const float4*)(y + (size_t)s0 * H_DIM + c);
  const float4* b = (const float4*)(y + (size_t)s1 * H_DIM + c);
  float4 a0 = a[0], a1 = a[1], b0 = b[0], b1 = b[1];
  float4 o0 = {a0.x + b0.x, a0.y + b0.y, a0.z + b0.z, a0.w + b0.w};
  float4 o1 = {a1.x + b1.x, a1.y + b1.y, a1.z + b1.z, a1.w + b1.w};
  float4* dst = (float4*)(out + (size_t)t * H_DIM + c);
  dst[0] = o0; dst[1] = o1;
}

extern "C" void kernel_launch(void* const* d_in, const int* in_sizes, int n_in,
                              void* d_out, int out_size, void* d_ws, size_t ws_size,
                              hipStream_t stream) {
  const float* x    = (const float*)d_in[0];
  const int*   eidx = (const int*)d_in[1];
  const float* ew   = (const float*)d_in[2];
  const float* gate = (const float*)d_in[3];
  const float* up   = (const float*)d_in[4];
  const float* down = (const float*)d_in[5];
  float* out = (float*)d_out;
  char* ws = (char*)d_ws;

  if (ws_size < WS_FULL) {
    hipMemsetAsync(d_out, 0, (size_t)NTOK * H_DIM * sizeof(float), stream);
    return;
  }

  int*      counts  = (int*)(ws + WS_COUNTS);
  int*      offsets = (int*)(ws + WS_OFFSETS);
  int*      tokid   = (int*)(ws + WS_TOKID);
  int*      slotOf  = (int*)(ws + WS_SLOT);
  float*    pairw   = (float*)(ws + WS_PAIRW);
  uint16_t* xg      = (uint16_t*)(ws + WS_XG);
  uint16_t* inter   = (uint16_t*)(ws + WS_INTER);
  float*    y       = (float*)(ws + WS_Y);
  uint16_t* gw      = (uint16_t*)(ws + WS_GW);
  uint16_t* uw      = (uint16_t*)(ws + WS_UW);
  uint16_t* dwp     = (uint16_t*)(ws + WS_DW);

  route_kernel<<<1, 256, 0, stream>>>(eidx, ew, counts, offsets, tokid, slotOf, pairw);
  gather_cast_kernel<<<NPAIR, 256, 0, stream>>>(x, tokid, xg);
  cast3_kernel<<<dim3(2048, 3), 256, 0, stream>>>(gate, up, down, gw, uw, dwp);

  gemm1_v3<<<dim3(I_DIM / 128, NPAIR / 256, NEXP), 512, 0, stream>>>(
      xg, gw, uw, counts, offsets, inter);
  gemm2_v3<<<dim3(H_DIM / 128, NPAIR / 256, NEXP), 512, 0, stream>>>(
      inter, dwp, counts, offsets, pairw, y);
  combine_kernel<<<NTOK, 256, 0, stream>>>(y, slotOf, out);
}

// Round 4
// 1362.245 us; speedup vs baseline: 1.1193x; 1.1193x over previous
//
#include <hip/hip_runtime.h>
#include <hip/hip_bf16.h>
#include <stdint.h>

// Problem constants: H=2048, I=4096, E=8, TOPK=2, B*S=4096
#define H_DIM 2048
#define I_DIM 4096
#define NEXP  8
#define NTOK  4096
#define NPAIR 8192
#define PAD_ROWS (NPAIR + 256)

// Workspace layout (bytes)
#define MiB (1024ull * 1024ull)
#define WS_COUNTS   0ull
#define WS_OFFSETS  256ull
#define WS_TOKID    1024ull
#define WS_SLOT     (64ull * 1024)
#define WS_PAIRW    (128ull * 1024)
#define WS_XG       (1ull * MiB)            // PAD_ROWS*H*2B = 34.6 MB
#define WS_INTER    (36ull * MiB)           // PAD_ROWS*I*2B = 69.2 MB
#define WS_Y        (104ull * MiB)          // PAD_ROWS*H*4B = 69.2 MB
#define WS_FULL     (172ull * MiB)

typedef __attribute__((ext_vector_type(8))) short bf16x8;
typedef __attribute__((ext_vector_type(4))) float f32x4;

#if defined(__has_builtin)
#if __has_builtin(__builtin_amdgcn_cvt_pk_bf16_f32)
#define HAVE_CVT_PK 1
#endif
#endif

__device__ __forceinline__ uint32_t bf16_bits_rne(float x) {
  uint32_t u = __float_as_uint(x);
  return (u + 0x7FFFu + ((u >> 16) & 1u)) >> 16;
}
__device__ __forceinline__ uint32_t pk_bf16(float a, float b) {
#ifdef HAVE_CVT_PK
  auto r = __builtin_amdgcn_cvt_pk_bf16_f32(a, b);
  return __builtin_bit_cast(uint32_t, r);
#else
  return bf16_bits_rne(a) | (bf16_bits_rne(b) << 16);
#endif
}
__device__ __forceinline__ uint16_t bf16_one(float x) {
  return (uint16_t)(pk_bf16(x, x) & 0xFFFFu);
}

// async global->LDS, 16B/lane: lane i lands at lds_base + 16*i (base wave-uniform)
__device__ __forceinline__ void async_load16(const void* g, void* l) {
  __builtin_amdgcn_global_load_lds(
      (const __attribute__((address_space(1))) void*)g,
      (__attribute__((address_space(3))) void*)l, 16, 0, 0);
}

#define WAIT_VM4()   do { asm volatile("s_waitcnt vmcnt(4)" ::: "memory"); __builtin_amdgcn_sched_barrier(0); } while (0)
#define WAIT_VM0()   do { asm volatile("s_waitcnt vmcnt(0)" ::: "memory"); __builtin_amdgcn_sched_barrier(0); } while (0)
#define WAIT_LGKM0() do { asm volatile("s_waitcnt lgkmcnt(0)" ::: "memory"); __builtin_amdgcn_sched_barrier(0); } while (0)
#define BARRIER()    do { __builtin_amdgcn_s_barrier(); asm volatile("" ::: "memory"); } while (0)
#define SBAR0()      __builtin_amdgcn_sched_barrier(0)

// ---------------- routing ----------------
__global__ void route_kernel(const int* __restrict__ idx, const float* __restrict__ wts,
                             int* __restrict__ ws_counts, int* __restrict__ ws_offsets,
                             int* __restrict__ tokid, int* __restrict__ slotOf,
                             float* __restrict__ pairw) {
  __shared__ int s_cnt[NEXP], s_off[NEXP], s_cur[NEXP];
  int tid = threadIdx.x;
  if (tid < NEXP) s_cnt[tid] = 0;
  __syncthreads();
  for (int p = tid; p < NPAIR; p += 256) atomicAdd(&s_cnt[idx[p]], 1);
  __syncthreads();
  if (tid == 0) {
    int acc = 0;
    for (int e = 0; e < NEXP; e++) { s_off[e] = acc; s_cur[e] = acc; acc += s_cnt[e]; }
  }
  __syncthreads();
  for (int p = tid; p < NPAIR; p += 256) {
    int e = idx[p];
    int slot = atomicAdd(&s_cur[e], 1);
    tokid[slot] = p >> 1;
    slotOf[p] = slot;
    pairw[slot] = wts[p];
  }
  if (tid < NEXP) { ws_counts[tid] = s_cnt[tid]; ws_offsets[tid] = s_off[tid]; }
}

// ---------------- gather routed rows of x, fp32 -> bf16 ----------------
__global__ void gather_cast_kernel(const float* __restrict__ x, const int* __restrict__ tokid,
                                   uint16_t* __restrict__ xg) {
  int p = blockIdx.x;
  int t = tokid[p];
  int c = threadIdx.x * 8;
  const float4* src = (const float4*)(x + (size_t)t * H_DIM + c);
  float4 v0 = src[0], v1 = src[1];
  uint4 o;
  o.x = pk_bf16(v0.x, v0.y); o.y = pk_bf16(v0.z, v0.w);
  o.z = pk_bf16(v1.x, v1.y); o.w = pk_bf16(v1.z, v1.w);
  *(uint4*)(xg + (size_t)p * H_DIM + c) = o;
}

// =====================================================================================
// GEMM1 v4 (v2 schedule + reg-staged fp32 B + static-buffer unroll):
// tile 256 rows x 64 dual-cols (gate+up), BK=64, 8 waves (4M x 2N), triple-buffered LDS.
// A: bf16 xg via global_load_lds (source pre-XOR-swizzled, linear dest).
// B: fp32 gate/up -> regs at iter start (for t+1), cvt_pk + swizzled ds_write at iter end
//    (HBM latency hidden under the MFMA phase). vmcnt(4) leaves A(t+2) in flight.
// =====================================================================================
#define NT1 (H_DIM / 64)            // 32
#define T1_ELE  (256 * 64 + 2 * 64 * 64)   // 24576 elems = 48KB
#define BG_OFF  (256 * 64)
#define BU_OFF  (256 * 64 + 64 * 64)

__global__ __launch_bounds__(512, 1)
void gemm1_v4(const uint16_t* __restrict__ xg,
              const float* __restrict__ gate, const float* __restrict__ up,
              const int* __restrict__ ws_counts, const int* __restrict__ ws_offsets,
              uint16_t* __restrict__ inter) {
  int e = blockIdx.z;
  int cnt = ws_counts[e];
  int rowTile = blockIdx.y;
  if (rowTile * 256 >= cnt) return;
  int off = ws_offsets[e];
  int colBase = blockIdx.x * 64;
  size_t rowBase = (size_t)off + (size_t)rowTile * 256;

  __shared__ uint16_t lds[3 * T1_ELE];    // 144 KB

  int tid = threadIdx.x, lane = tid & 63, w = tid >> 6;
  int r8 = lane >> 3, g8 = lane & 7;
  int gsw = (g8 ^ r8) << 3;               // A source pre-swizzle (elems)

  // A: 32 rows per wave, 4 chunks of 8 rows; LDS dest linear at w*2048 + c*512
  const uint16_t* aSrc[4];
#pragma unroll
  for (int c = 0; c < 4; c++)
    aSrc[c] = xg + (rowBase + (size_t)(w * 32 + c * 8 + r8)) * H_DIM + gsw;

  // B fp32: 8 rows per wave per matrix; lane covers 8 contiguous floats (g8*8..+8)
  const float* gSrc = gate + ((size_t)e * I_DIM + colBase + w * 8 + r8) * H_DIM + g8 * 8;
  const float* uSrc = up   + ((size_t)e * I_DIM + colBase + w * 8 + r8) * H_DIM + g8 * 8;
  // swizzled B write addresses (elems): row = w*8+r8, col-group = g8 ^ r8
  const int bgWr = BG_OFF + (w * 8 + r8) * 64 + ((g8 ^ r8) << 3);
  const int buWr = BU_OFF + (w * 8 + r8) * 64 + ((g8 ^ r8) << 3);

  int wr = w >> 1, wc = w & 1;
  int wm = wr * 64, wn = wc * 32;
  int lcol = lane & 15, quad = lane >> 4;
  int sx = (lcol & 7) << 3;

  f32x4 accg[4][2], accu[4][2];
  f32x4 zero = {0.f, 0.f, 0.f, 0.f};
#pragma unroll
  for (int mi = 0; mi < 4; mi++)
#pragma unroll
    for (int ni = 0; ni < 2; ni++) { accg[mi][ni] = zero; accu[mi][ni] = zero; }

#define COMP1(LB) do {                                                                 \
    _Pragma("unroll")                                                                  \
    for (int ks = 0; ks < 2; ks++) {                                                   \
      const int krs = (ks * 32 + quad * 8) ^ sx;                                       \
      bf16x8 af[4], bgf[2], buf_[2];                                                   \
      _Pragma("unroll") for (int mi = 0; mi < 4; mi++)                                 \
        af[mi] = *(const bf16x8*)((LB) + (wm + mi * 16 + lcol) * 64 + krs);            \
      _Pragma("unroll") for (int ni = 0; ni < 2; ni++) {                               \
        bgf[ni]  = *(const bf16x8*)((LB) + BG_OFF + (wn + ni * 16 + lcol) * 64 + krs); \
        buf_[ni] = *(const bf16x8*)((LB) + BU_OFF + (wn + ni * 16 + lcol) * 64 + krs); \
      }                                                                                \
      __builtin_amdgcn_s_setprio(1);                                                   \
      _Pragma("unroll") for (int mi = 0; mi < 4; mi++)                                 \
        _Pragma("unroll") for (int ni = 0; ni < 2; ni++) {                             \
          accg[mi][ni] = __builtin_amdgcn_mfma_f32_16x16x32_bf16(af[mi], bgf[ni],      \
                                                                 accg[mi][ni], 0, 0, 0);\
          accu[mi][ni] = __builtin_amdgcn_mfma_f32_16x16x32_bf16(af[mi], buf_[ni],     \
                                                                 accu[mi][ni], 0, 0, 0);\
        }                                                                              \
      __builtin_amdgcn_s_setprio(0);                                                   \
    }                                                                                  \
  } while (0)

#define ITER1(T, B0) do {                                                              \
    const int t_ = (T);                                                                \
    uint16_t* lb  = lds + (B0) * T1_ELE;                                               \
    uint16_t* lbn = lds + (((B0) + 1) % 3) * T1_ELE;                                   \
    uint16_t* lb2 = lds + (((B0) + 2) % 3) * T1_ELE;                                   \
    float4 g0, g1, u0, u1;                                                             \
    const bool hasB = (t_ + 1 < NT1);                                                  \
    if (hasB) {                                                                        \
      const float4* gp = (const float4*)(gSrc + (size_t)(t_ + 1) * 64);                \
      g0 = gp[0]; g1 = gp[1];                                                          \
      const float4* upp = (const float4*)(uSrc + (size_t)(t_ + 1) * 64);               \
      u0 = upp[0]; u1 = upp[1];                                                        \
    }                                                                                  \
    SBAR0();                                                                           \
    if (t_ + 2 < NT1) {                                                                \
      const int ko = (t_ + 2) * 64;                                                    \
      async_load16(aSrc[0] + ko, lb2 + w * 2048 + 0 * 512);                            \
      async_load16(aSrc[1] + ko, lb2 + w * 2048 + 1 * 512);                            \
      async_load16(aSrc[2] + ko, lb2 + w * 2048 + 2 * 512);                            \
      async_load16(aSrc[3] + ko, lb2 + w * 2048 + 3 * 512);                            \
    }                                                                                  \
    SBAR0();                                                                           \
    COMP1(lb);                                                                         \
    if (t_ + 2 < NT1) { WAIT_VM4(); } else { WAIT_VM0(); }                             \
    if (hasB) {                                                                        \
      uint4 og = { pk_bf16(g0.x, g0.y), pk_bf16(g0.z, g0.w),                           \
                   pk_bf16(g1.x, g1.y), pk_bf16(g1.z, g1.w) };                         \
      uint4 ou = { pk_bf16(u0.x, u0.y), pk_bf16(u0.z, u0.w),                           \
                   pk_bf16(u1.x, u1.y), pk_bf16(u1.z, u1.w) };                         \
      *(uint4*)(lbn + bgWr) = og;                                                      \
      *(uint4*)(lbn + buWr) = ou;                                                      \
      WAIT_LGKM0();                                                                    \
    }                                                                                  \
    BARRIER();                                                                         \
  } while (0)

  // prologue: A(0)->buf0, B(0) regs, A(1)->buf1; vmcnt(4) leaves A(1); write B(0)->buf0
  {
#pragma unroll
    for (int c = 0; c < 4; c++) async_load16(aSrc[c], lds + w * 2048 + c * 512);
    SBAR0();
    const float4* gp = (const float4*)gSrc;
    float4 g0 = gp[0], g1 = gp[1];
    const float4* upp = (const float4*)uSrc;
    float4 u0 = upp[0], u1 = upp[1];
    SBAR0();
#pragma unroll
    for (int c = 0; c < 4; c++) async_load16(aSrc[c] + 64, lds + T1_ELE + w * 2048 + c * 512);
    WAIT_VM4();
    uint4 og = { pk_bf16(g0.x, g0.y), pk_bf16(g0.z, g0.w),
                 pk_bf16(g1.x, g1.y), pk_bf16(g1.z, g1.w) };
    uint4 ou = { pk_bf16(u0.x, u0.y), pk_bf16(u0.z, u0.w),
                 pk_bf16(u1.x, u1.y), pk_bf16(u1.z, u1.w) };
    *(uint4*)(lds + bgWr) = og;
    *(uint4*)(lds + buWr) = ou;
    WAIT_LGKM0();
    BARRIER();
  }

  for (int t = 0; t < 30; t += 3) { ITER1(t, 0); ITER1(t + 1, 1); ITER1(t + 2, 2); }
  ITER1(30, 0); ITER1(31, 1);
#undef ITER1
#undef COMP1

  // epilogue: silu(g)*u -> bf16 inter. C frag: col=lane&15, row=quad*4+r
  int col0 = colBase + wn;
#pragma unroll
  for (int mi = 0; mi < 4; mi++) {
#pragma unroll
    for (int r = 0; r < 4; r++) {
      int localRow = rowTile * 256 + wm + mi * 16 + quad * 4 + r;
      if (localRow < cnt) {
        size_t prow = (size_t)off + localRow;
#pragma unroll
        for (int ni = 0; ni < 2; ni++) {
          float g = accg[mi][ni][r], u = accu[mi][ni][r];
          float v = (g / (1.f + __expf(-g))) * u;
          inter[prow * I_DIM + col0 + ni * 16 + lcol] = bf16_one(v);
        }
      }
    }
  }
}

// =====================================================================================
// GEMM2 v4: same structure. tile 256 rows x 128 cols, BK=64, 8 waves (4M x 2N).
// A: inter bf16 via global_load_lds. B: down fp32 reg-staged (2 chunks of 8 rows).
// =====================================================================================
#define NT2 (I_DIM / 64)            // 64
#define T2_ELE  (256 * 64 + 128 * 64)      // 24576 elems = 48KB
#define BD_OFF  (256 * 64)

__global__ __launch_bounds__(512, 1)
void gemm2_v4(const uint16_t* __restrict__ inter, const float* __restrict__ down,
              const int* __restrict__ ws_counts, const int* __restrict__ ws_offsets,
              const float* __restrict__ pairw, float* __restrict__ y) {
  int e = blockIdx.z;
  int cnt = ws_counts[e];
  int rowTile = blockIdx.y;
  if (rowTile * 256 >= cnt) return;
  int off = ws_offsets[e];
  int colBase = blockIdx.x * 128;
  size_t rowBase = (size_t)off + (size_t)rowTile * 256;

  __shared__ uint16_t lds[3 * T2_ELE];    // 144 KB

  int tid = threadIdx.x, lane = tid & 63, w = tid >> 6;
  int r8 = lane >> 3, g8 = lane & 7;
  int gsw = (g8 ^ r8) << 3;

  const uint16_t* aSrc[4];
#pragma unroll
  for (int c = 0; c < 4; c++)
    aSrc[c] = inter + (rowBase + (size_t)(w * 32 + c * 8 + r8)) * I_DIM + gsw;

  // B fp32: 16 rows per wave (2 chunks of 8)
  const float* dSrc0 = down + ((size_t)e * H_DIM + colBase + w * 16 + 0 + r8) * I_DIM + g8 * 8;
  const float* dSrc1 = down + ((size_t)e * H_DIM + colBase + w * 16 + 8 + r8) * I_DIM + g8 * 8;
  const int bdWr0 = BD_OFF + (w * 16 + 0 + r8) * 64 + ((g8 ^ r8) << 3);
  const int bdWr1 = BD_OFF + (w * 16 + 8 + r8) * 64 + ((g8 ^ r8) << 3);

  int wr = w >> 1, wc = w & 1;
  int wm = wr * 64, wn = wc * 64;
  int lcol = lane & 15, quad = lane >> 4;
  int sx = (lcol & 7) << 3;

  f32x4 acc[4][4];
  f32x4 zero = {0.f, 0.f, 0.f, 0.f};
#pragma unroll
  for (int mi = 0; mi < 4; mi++)
#pragma unroll
    for (int ni = 0; ni < 4; ni++) acc[mi][ni] = zero;

#define COMP2(LB) do {                                                                 \
    _Pragma("unroll")                                                                  \
    for (int ks = 0; ks < 2; ks++) {                                                   \
      const int krs = (ks * 32 + quad * 8) ^ sx;                                       \
      bf16x8 af[4], bb[4];                                                             \
      _Pragma("unroll") for (int mi = 0; mi < 4; mi++)                                 \
        af[mi] = *(const bf16x8*)((LB) + (wm + mi * 16 + lcol) * 64 + krs);            \
      _Pragma("unroll") for (int ni = 0; ni < 4; ni++)                                 \
        bb[ni] = *(const bf16x8*)((LB) + BD_OFF + (wn + ni * 16 + lcol) * 64 + krs);   \
      __builtin_amdgcn_s_setprio(1);                                                   \
      _Pragma("unroll") for (int mi = 0; mi < 4; mi++)                                 \
        _Pragma("unroll") for (int ni = 0; ni < 4; ni++)                               \
          acc[mi][ni] = __builtin_amdgcn_mfma_f32_16x16x32_bf16(af[mi], bb[ni],        \
                                                                acc[mi][ni], 0, 0, 0); \
      __builtin_amdgcn_s_setprio(0);                                                   \
    }                                                                                  \
  } while (0)

#define ITER2(T, B0) do {                                                              \
    const int t_ = (T);                                                                \
    uint16_t* lb  = lds + (B0) * T2_ELE;                                               \
    uint16_t* lbn = lds + (((B0) + 1) % 3) * T2_ELE;                                   \
    uint16_t* lb2 = lds + (((B0) + 2) % 3) * T2_ELE;                                   \
    float4 d00, d01, d10, d11;                                                         \
    const bool hasB = (t_ + 1 < NT2);                                                  \
    if (hasB) {                                                                        \
      const float4* p0 = (const float4*)(dSrc0 + (size_t)(t_ + 1) * 64);               \
      d00 = p0[0]; d01 = p0[1];                                                        \
      const float4* p1 = (const float4*)(dSrc1 + (size_t)(t_ + 1) * 64);               \
      d10 = p1[0]; d11 = p1[1];                                                        \
    }                                                                                  \
    SBAR0();                                                                           \
    if (t_ + 2 < NT2) {                                                                \
      const int ko = (t_ + 2) * 64;                                                    \
      async_load16(aSrc[0] + ko, lb2 + w * 2048 + 0 * 512);                            \
      async_load16(aSrc[1] + ko, lb2 + w * 2048 + 1 * 512);                            \
      async_load16(aSrc[2] + ko, lb2 + w * 2048 + 2 * 512);                            \
      async_load16(aSrc[3] + ko, lb2 + w * 2048 + 3 * 512);                            \
    }                                                                                  \
    SBAR0();                                                                           \
    COMP2(lb);                                                                         \
    if (t_ + 2 < NT2) { WAIT_VM4(); } else { WAIT_VM0(); }                             \
    if (hasB) {                                                                        \
      uint4 o0 = { pk_bf16(d00.x, d00.y), pk_bf16(d00.z, d00.w),                       \
                   pk_bf16(d01.x, d01.y), pk_bf16(d01.z, d01.w) };                     \
      uint4 o1 = { pk_bf16(d10.x, d10.y), pk_bf16(d10.z, d10.w),                       \
                   pk_bf16(d11.x, d11.y), pk_bf16(d11.z, d11.w) };                     \
      *(uint4*)(lbn + bdWr0) = o0;                                                     \
      *(uint4*)(lbn + bdWr1) = o1;                                                     \
      WAIT_LGKM0();                                                                    \
    }                                                                                  \
    BARRIER();                                                                         \
  } while (0)

  // prologue
  {
#pragma unroll
    for (int c = 0; c < 4; c++) async_load16(aSrc[c], lds + w * 2048 + c * 512);
    SBAR0();
    const float4* p0 = (const float4*)dSrc0;
    float4 d00 = p0[0], d01 = p0[1];
    const float4* p1 = (const float4*)dSrc1;
    float4 d10 = p1[0], d11 = p1[1];
    SBAR0();
#pragma unroll
    for (int c = 0; c < 4; c++) async_load16(aSrc[c] + 64, lds + T2_ELE + w * 2048 + c * 512);
    WAIT_VM4();
    uint4 o0 = { pk_bf16(d00.x, d00.y), pk_bf16(d00.z, d00.w),
                 pk_bf16(d01.x, d01.y), pk_bf16(d01.z, d01.w) };
    uint4 o1 = { pk_bf16(d10.x, d10.y), pk_bf16(d10.z, d10.w),
                 pk_bf16(d11.x, d11.y), pk_bf16(d11.z, d11.w) };
    *(uint4*)(lds + bdWr0) = o0;
    *(uint4*)(lds + bdWr1) = o1;
    WAIT_LGKM0();
    BARRIER();
  }

  for (int t = 0; t < 60; t += 3) { ITER2(t, 0); ITER2(t + 1, 1); ITER2(t + 2, 2); }
  ITER2(60, 0); ITER2(61, 1); ITER2(62, 2); ITER2(63, 0);
#undef ITER2
#undef COMP2

  int col0 = colBase + wn;
#pragma unroll
  for (int mi = 0; mi < 4; mi++) {
#pragma unroll
    for (int r = 0; r < 4; r++) {
      int localRow = rowTile * 256 + wm + mi * 16 + quad * 4 + r;
      if (localRow < cnt) {
        size_t prow = (size_t)off + localRow;
        float wgt = pairw[prow];
        float* yr = y + prow * H_DIM + col0;
#pragma unroll
        for (int ni = 0; ni < 4; ni++)
          yr[ni * 16 + lcol] = acc[mi][ni][r] * wgt;
      }
    }
  }
}

// ---------------- combine: out[t] = y[slot(2t)] + y[slot(2t+1)] ----------------
__global__ void combine_kernel(const float* __restrict__ y, const int* __restrict__ slotOf,
                               float* __restrict__ out) {
  int t = blockIdx.x;
  int s0 = slotOf[2 * t], s1 = slotOf[2 * t + 1];
  int c = threadIdx.x * 8;
  const float4* a = (const float4*)(y + (size_t)s0 * H_DIM + c);
  const float4* b = (const float4*)(y + (size_t)s1 * H_DIM + c);
  float4 a0 = a[0], a1 = a[1], b0 = b[0], b1 = b[1];
  float4 o0 = {a0.x + b0.x, a0.y + b0.y, a0.z + b0.z, a0.w + b0.w};
  float4 o1 = {a1.x + b1.x, a1.y + b1.y, a1.z + b1.z, a1.w + b1.w};
  float4* dst = (float4*)(out + (size_t)t * H_DIM + c);
  dst[0] = o0; dst[1] = o1;
}

extern "C" void kernel_launch(void* const* d_in, const int* in_sizes, int n_in,
                              void* d_out, int out_size, void* d_ws, size_t ws_size,
                              hipStream_t stream) {
  const float* x    = (const float*)d_in[0];
  const int*   eidx = (const int*)d_in[1];
  const float* ew   = (const float*)d_in[2];
  const float* gate = (const float*)d_in[3];
  const float* up   = (const float*)d_in[4];
  const float* down = (const float*)d_in[5];
  float* out = (float*)d_out;
  char* ws = (char*)d_ws;

  if (ws_size < WS_FULL) {
    hipMemsetAsync(d_out, 0, (size_t)NTOK * H_DIM * sizeof(float), stream);
    return;
  }

  int*      counts  = (int*)(ws + WS_COUNTS);
  int*      offsets = (int*)(ws + WS_OFFSETS);
  int*      tokid   = (int*)(ws + WS_TOKID);
  int*      slotOf  = (int*)(ws + WS_SLOT);
  float*    pairw   = (float*)(ws + WS_PAIRW);
  uint16_t* xg      = (uint16_t*)(ws + WS_XG);
  uint16_t* inter   = (uint16_t*)(ws + WS_INTER);
  float*    y       = (float*)(ws + WS_Y);

  route_kernel<<<1, 256, 0, stream>>>(eidx, ew, counts, offsets, tokid, slotOf, pairw);
  gather_cast_kernel<<<NPAIR, 256, 0, stream>>>(x, tokid, xg);

  gemm1_v4<<<dim3(I_DIM / 64, NPAIR / 256, NEXP), 512, 0, stream>>>(
      xg, gate, up, counts, offsets, inter);
  gemm2_v4<<<dim3(H_DIM / 128, NPAIR / 256, NEXP), 512, 0, stream>>>(
      inter, down, counts, offsets, pairw, y);
  combine_kernel<<<NTOK, 256, 0, stream>>>(y, slotOf, out);
}

// Round 5
// 1312.085 us; speedup vs baseline: 1.1621x; 1.0382x over previous
//
#include <hip/hip_runtime.h>
#include <hip/hip_bf16.h>
#include <stdint.h>

// Problem constants: H=2048, I=4096, E=8, TOPK=2, B*S=4096
#define H_DIM 2048
#define I_DIM 4096
#define NEXP  8
#define NTOK  4096
#define NPAIR 8192
#define PAD_ROWS (NPAIR + 256)

// Workspace layout (bytes)
#define MiB (1024ull * 1024ull)
#define WS_COUNTS   0ull
#define WS_OFFSETS  256ull
#define WS_TOKID    1024ull
#define WS_SLOT     (64ull * 1024)
#define WS_PAIRW    (128ull * 1024)
#define WS_XG       (1ull * MiB)            // PAD_ROWS*H*2B = 34.6 MB
#define WS_INTER    (36ull * MiB)           // PAD_ROWS*I*2B = 69.2 MB
#define WS_Y        (104ull * MiB)          // PAD_ROWS*H*4B = 69.2 MB
#define WS_GW       (176ull * MiB)          // E*I*H bf16 = 128 MiB
#define WS_UW       (304ull * MiB)
#define WS_DW       (432ull * MiB)
#define WS_FULL     (560ull * MiB)

typedef __attribute__((ext_vector_type(8))) short bf16x8;
typedef __attribute__((ext_vector_type(4))) float f32x4;

#if defined(__has_builtin)
#if __has_builtin(__builtin_amdgcn_cvt_pk_bf16_f32)
#define HAVE_CVT_PK 1
#endif
#endif

__device__ __forceinline__ uint32_t bf16_bits_rne(float x) {
  uint32_t u = __float_as_uint(x);
  return (u + 0x7FFFu + ((u >> 16) & 1u)) >> 16;
}
__device__ __forceinline__ uint32_t pk_bf16(float a, float b) {
#ifdef HAVE_CVT_PK
  auto r = __builtin_amdgcn_cvt_pk_bf16_f32(a, b);
  return __builtin_bit_cast(uint32_t, r);
#else
  return bf16_bits_rne(a) | (bf16_bits_rne(b) << 16);
#endif
}
__device__ __forceinline__ uint16_t bf16_one(float x) {
  return (uint16_t)(pk_bf16(x, x) & 0xFFFFu);
}

// async global->LDS, 16B/lane: lane i lands at lds_base + 16*i (base wave-uniform)
__device__ __forceinline__ void async_load16(const void* g, void* l) {
  __builtin_amdgcn_global_load_lds(
      (const __attribute__((address_space(1))) void*)g,
      (__attribute__((address_space(3))) void*)l, 16, 0, 0);
}

#define WAIT_VM6()   do { asm volatile("s_waitcnt vmcnt(6)" ::: "memory"); __builtin_amdgcn_sched_barrier(0); } while (0)
#define WAIT_VM0()   do { asm volatile("s_waitcnt vmcnt(0)" ::: "memory"); __builtin_amdgcn_sched_barrier(0); } while (0)
#define WAIT_LGKM0() do { asm volatile("s_waitcnt lgkmcnt(0)" ::: "memory"); __builtin_amdgcn_sched_barrier(0); } while (0)
#define BARRIER()    do { __builtin_amdgcn_s_barrier(); asm volatile("" ::: "memory"); } while (0)

// ---------------- routing ----------------
__global__ void route_kernel(const int* __restrict__ idx, const float* __restrict__ wts,
                             int* __restrict__ ws_counts, int* __restrict__ ws_offsets,
                             int* __restrict__ tokid, int* __restrict__ slotOf,
                             float* __restrict__ pairw) {
  __shared__ int s_cnt[NEXP], s_off[NEXP], s_cur[NEXP];
  int tid = threadIdx.x;
  if (tid < NEXP) s_cnt[tid] = 0;
  __syncthreads();
  for (int p = tid; p < NPAIR; p += 256) atomicAdd(&s_cnt[idx[p]], 1);
  __syncthreads();
  if (tid == 0) {
    int acc = 0;
    for (int e = 0; e < NEXP; e++) { s_off[e] = acc; s_cur[e] = acc; acc += s_cnt[e]; }
  }
  __syncthreads();
  for (int p = tid; p < NPAIR; p += 256) {
    int e = idx[p];
    int slot = atomicAdd(&s_cur[e], 1);
    tokid[slot] = p >> 1;
    slotOf[p] = slot;
    pairw[slot] = wts[p];
  }
  if (tid < NEXP) { ws_counts[tid] = s_cnt[tid]; ws_offsets[tid] = s_off[tid]; }
}

// ---------------- gather routed rows of x, fp32 -> bf16 ----------------
__global__ void gather_cast_kernel(const float* __restrict__ x, const int* __restrict__ tokid,
                                   uint16_t* __restrict__ xg) {
  int p = blockIdx.x;
  int t = tokid[p];
  int c = threadIdx.x * 8;
  const float4* src = (const float4*)(x + (size_t)t * H_DIM + c);
  float4 v0 = src[0], v1 = src[1];
  uint4 o;
  o.x = pk_bf16(v0.x, v0.y); o.y = pk_bf16(v0.z, v0.w);
  o.z = pk_bf16(v1.x, v1.y); o.w = pk_bf16(v1.z, v1.w);
  *(uint4*)(xg + (size_t)p * H_DIM + c) = o;
}

// ---------------- one-shot weight cast fp32 -> bf16 ----------------
__global__ void cast3_kernel(const float* __restrict__ g, const float* __restrict__ u,
                             const float* __restrict__ d,
                             uint16_t* __restrict__ gw, uint16_t* __restrict__ uw,
                             uint16_t* __restrict__ dw) {
  const float* src = blockIdx.y == 0 ? g : (blockIdx.y == 1 ? u : d);
  uint16_t*    dst = blockIdx.y == 0 ? gw : (blockIdx.y == 1 ? uw : dw);
  const long long n8 = (long long)NEXP * I_DIM * H_DIM / 8;
  long long stride = (long long)gridDim.x * blockDim.x;
  for (long long i = (long long)blockIdx.x * blockDim.x + threadIdx.x; i < n8; i += stride) {
    const float4* s = (const float4*)(src + i * 8);
    float4 a = s[0], b = s[1];
    uint4 o = { pk_bf16(a.x, a.y), pk_bf16(a.z, a.w), pk_bf16(b.x, b.y), pk_bf16(b.z, b.w) };
    *(uint4*)(dst + i * 8) = o;
  }
}

// =====================================================================================
// GEMM1 v5 = v2 machinery (256x64-dual tile, BK=64, 8 waves 4Mx2N, triple-buffered LDS,
// XOR-swizzled conflict-free layout, counted vmcnt(6)) + 2-phase K-tile split:
// each ks-half gets {8 ds_read + 3 stage instr -> barrier -> lgkm0 -> setprio+16 MFMA ->
// barrier}; vmcnt(6) only at phase-2 end. Ledger identical to v2.
// =====================================================================================
#define T1_A    (256 * 64)
#define T1_B    (64 * 64)
#define T1_ELE  (T1_A + 2 * T1_B)   // 24576 elems = 48KB

__global__ __launch_bounds__(512, 1)
void gemm1_v5(const uint16_t* __restrict__ xg,
              const uint16_t* __restrict__ gw, const uint16_t* __restrict__ uw,
              const int* __restrict__ ws_counts, const int* __restrict__ ws_offsets,
              uint16_t* __restrict__ inter) {
  int e = blockIdx.z;
  int cnt = ws_counts[e];
  int rowTile = blockIdx.y;
  if (rowTile * 256 >= cnt) return;
  int off = ws_offsets[e];
  int colBase = blockIdx.x * 64;
  size_t rowBase = (size_t)off + (size_t)rowTile * 256;

  __shared__ uint16_t lds[3 * T1_ELE];    // 144 KB

  int tid = threadIdx.x, lane = tid & 63, w = tid >> 6;
  int r8 = lane >> 3;
  int gsw = ((lane & 7) ^ r8) << 3;        // pre-swizzled source col (elements)

  const uint16_t* srcA[4];
#pragma unroll
  for (int c = 0; c < 4; c++)
    srcA[c] = xg + (rowBase + (size_t)(w * 32 + c * 8 + r8)) * H_DIM + gsw;
  const uint16_t* srcG = gw + ((size_t)e * I_DIM + colBase + w * 8 + r8) * H_DIM + gsw;
  const uint16_t* srcU = uw + ((size_t)e * I_DIM + colBase + w * 8 + r8) * H_DIM + gsw;

  const int dA = w * 2048;
  const int dG = T1_A + w * 512;
  const int dU = T1_A + T1_B + w * 512;

  f32x4 accg[4][2], accu[4][2];
  f32x4 zero = {0.f, 0.f, 0.f, 0.f};
#pragma unroll
  for (int mi = 0; mi < 4; mi++)
#pragma unroll
    for (int ni = 0; ni < 2; ni++) { accg[mi][ni] = zero; accu[mi][ni] = zero; }

  int wr = w >> 1, wc = w & 1;
  int wm = wr * 64, wn = wc * 32;
  int lcol = lane & 15, quad = lane >> 4;
  int sx = (lcol & 7) << 3;

  // full-tile stage (prologue only)
  auto STG = [&](int kt, int b) {
    uint16_t* lb = lds + b * T1_ELE;
    int ko = kt * 64;
#pragma unroll
    for (int c = 0; c < 4; c++) async_load16(srcA[c] + ko, lb + dA + c * 512);
    async_load16(srcG + ko, lb + dG);
    async_load16(srcU + ko, lb + dU);
  };

  STG(0, 0); STG(1, 1);
  WAIT_VM6();
  BARRIER();

  const int NT = H_DIM / 64;               // 32
  for (int t = 0; t < NT; ++t) {
    const int b = t % 3, b2 = (t + 2) % 3;
    uint16_t* lb  = lds + b * T1_ELE;
    uint16_t* lb2 = lds + b2 * T1_ELE;
    const bool pre = (t + 2 < NT);
    const int ko = (t + 2) * 64;

    // ---- phase 1 (ks = 0) ----
    {
      const int krs = (quad * 8) ^ sx;
      bf16x8 af[4], bg_[2], bu_[2];
#pragma unroll
      for (int mi = 0; mi < 4; mi++)
        af[mi] = *(const bf16x8*)(lb + (wm + mi * 16 + lcol) * 64 + krs);
#pragma unroll
      for (int ni = 0; ni < 2; ni++) {
        bg_[ni] = *(const bf16x8*)(lb + T1_A + (wn + ni * 16 + lcol) * 64 + krs);
        bu_[ni] = *(const bf16x8*)(lb + T1_A + T1_B + (wn + ni * 16 + lcol) * 64 + krs);
      }
      if (pre) {
        async_load16(srcA[0] + ko, lb2 + dA + 0 * 512);
        async_load16(srcA[1] + ko, lb2 + dA + 1 * 512);
        async_load16(srcA[2] + ko, lb2 + dA + 2 * 512);
      }
      BARRIER();
      WAIT_LGKM0();
      __builtin_amdgcn_s_setprio(1);
#pragma unroll
      for (int mi = 0; mi < 4; mi++)
#pragma unroll
        for (int ni = 0; ni < 2; ni++) {
          accg[mi][ni] = __builtin_amdgcn_mfma_f32_16x16x32_bf16(af[mi], bg_[ni], accg[mi][ni], 0, 0, 0);
          accu[mi][ni] = __builtin_amdgcn_mfma_f32_16x16x32_bf16(af[mi], bu_[ni], accu[mi][ni], 0, 0, 0);
        }
      __builtin_amdgcn_s_setprio(0);
      BARRIER();
    }
    // ---- phase 2 (ks = 1) ----
    {
      const int krs = (32 + quad * 8) ^ sx;
      bf16x8 af[4], bg_[2], bu_[2];
#pragma unroll
      for (int mi = 0; mi < 4; mi++)
        af[mi] = *(const bf16x8*)(lb + (wm + mi * 16 + lcol) * 64 + krs);
#pragma unroll
      for (int ni = 0; ni < 2; ni++) {
        bg_[ni] = *(const bf16x8*)(lb + T1_A + (wn + ni * 16 + lcol) * 64 + krs);
        bu_[ni] = *(const bf16x8*)(lb + T1_A + T1_B + (wn + ni * 16 + lcol) * 64 + krs);
      }
      if (pre) {
        async_load16(srcA[3] + ko, lb2 + dA + 3 * 512);
        async_load16(srcG + ko, lb2 + dG);
        async_load16(srcU + ko, lb2 + dU);
      }
      BARRIER();
      WAIT_LGKM0();
      __builtin_amdgcn_s_setprio(1);
#pragma unroll
      for (int mi = 0; mi < 4; mi++)
#pragma unroll
        for (int ni = 0; ni < 2; ni++) {
          accg[mi][ni] = __builtin_amdgcn_mfma_f32_16x16x32_bf16(af[mi], bg_[ni], accg[mi][ni], 0, 0, 0);
          accu[mi][ni] = __builtin_amdgcn_mfma_f32_16x16x32_bf16(af[mi], bu_[ni], accu[mi][ni], 0, 0, 0);
        }
      __builtin_amdgcn_s_setprio(0);
      if (pre) { WAIT_VM6(); } else { WAIT_VM0(); }
      BARRIER();
    }
  }

  // epilogue: silu(g)*u -> bf16 inter.  C layout: col=lane&15, row=quad*4+reg
  int col0 = colBase + wn;
#pragma unroll
  for (int mi = 0; mi < 4; mi++) {
#pragma unroll
    for (int r = 0; r < 4; r++) {
      int localRow = rowTile * 256 + wm + mi * 16 + quad * 4 + r;
      if (localRow < cnt) {
        size_t prow = (size_t)off + localRow;
#pragma unroll
        for (int ni = 0; ni < 2; ni++) {
          float g = accg[mi][ni][r], u = accu[mi][ni][r];
          float v = (g / (1.f + __expf(-g))) * u;
          inter[prow * I_DIM + col0 + ni * 16 + lcol] = bf16_one(v);
        }
      }
    }
  }
}

// =====================================================================================
// GEMM2 v5: same 2-phase split. tile 256x128, BK=64, triple-buffered, vmcnt(6).
// =====================================================================================
#define T2_A    (256 * 64)
#define T2_B    (128 * 64)
#define T2_ELE  (T2_A + T2_B)       // 24576 elems = 48KB

__global__ __launch_bounds__(512, 1)
void gemm2_v5(const uint16_t* __restrict__ inter, const uint16_t* __restrict__ dw,
              const int* __restrict__ ws_counts, const int* __restrict__ ws_offsets,
              const float* __restrict__ pairw, float* __restrict__ y) {
  int e = blockIdx.z;
  int cnt = ws_counts[e];
  int rowTile = blockIdx.y;
  if (rowTile * 256 >= cnt) return;
  int off = ws_offsets[e];
  int colBase = blockIdx.x * 128;
  size_t rowBase = (size_t)off + (size_t)rowTile * 256;

  __shared__ uint16_t lds[3 * T2_ELE];    // 144 KB

  int tid = threadIdx.x, lane = tid & 63, w = tid >> 6;
  int r8 = lane >> 3;
  int gsw = ((lane & 7) ^ r8) << 3;

  const uint16_t* srcA[4];
#pragma unroll
  for (int c = 0; c < 4; c++)
    srcA[c] = inter + (rowBase + (size_t)(w * 32 + c * 8 + r8)) * I_DIM + gsw;
  const uint16_t* srcB[2];
#pragma unroll
  for (int c = 0; c < 2; c++)
    srcB[c] = dw + ((size_t)e * H_DIM + colBase + w * 16 + c * 8 + r8) * I_DIM + gsw;

  const int dA = w * 2048;
  const int dB = T2_A + w * 1024;

  f32x4 acc[4][4];
  f32x4 zero = {0.f, 0.f, 0.f, 0.f};
#pragma unroll
  for (int mi = 0; mi < 4; mi++)
#pragma unroll
    for (int ni = 0; ni < 4; ni++) acc[mi][ni] = zero;

  int wr = w >> 1, wc = w & 1;
  int wm = wr * 64, wn = wc * 64;
  int lcol = lane & 15, quad = lane >> 4;
  int sx = (lcol & 7) << 3;

  auto STG = [&](int kt, int b) {
    uint16_t* lb = lds + b * T2_ELE;
    int ko = kt * 64;
#pragma unroll
    for (int c = 0; c < 4; c++) async_load16(srcA[c] + ko, lb + dA + c * 512);
#pragma unroll
    for (int c = 0; c < 2; c++) async_load16(srcB[c] + ko, lb + dB + c * 512);
  };

  STG(0, 0); STG(1, 1);
  WAIT_VM6();
  BARRIER();

  const int NT = I_DIM / 64;               // 64
  for (int t = 0; t < NT; ++t) {
    const int b = t % 3, b2 = (t + 2) % 3;
    uint16_t* lb  = lds + b * T2_ELE;
    uint16_t* lb2 = lds + b2 * T2_ELE;
    const bool pre = (t + 2 < NT);
    const int ko = (t + 2) * 64;

    // ---- phase 1 (ks = 0) ----
    {
      const int krs = (quad * 8) ^ sx;
      bf16x8 af[4], bb[4];
#pragma unroll
      for (int mi = 0; mi < 4; mi++)
        af[mi] = *(const bf16x8*)(lb + (wm + mi * 16 + lcol) * 64 + krs);
#pragma unroll
      for (int ni = 0; ni < 4; ni++)
        bb[ni] = *(const bf16x8*)(lb + T2_A + (wn + ni * 16 + lcol) * 64 + krs);
      if (pre) {
        async_load16(srcA[0] + ko, lb2 + dA + 0 * 512);
        async_load16(srcA[1] + ko, lb2 + dA + 1 * 512);
        async_load16(srcA[2] + ko, lb2 + dA + 2 * 512);
      }
      BARRIER();
      WAIT_LGKM0();
      __builtin_amdgcn_s_setprio(1);
#pragma unroll
      for (int mi = 0; mi < 4; mi++)
#pragma unroll
        for (int ni = 0; ni < 4; ni++)
          acc[mi][ni] = __builtin_amdgcn_mfma_f32_16x16x32_bf16(af[mi], bb[ni], acc[mi][ni], 0, 0, 0);
      __builtin_amdgcn_s_setprio(0);
      BARRIER();
    }
    // ---- phase 2 (ks = 1) ----
    {
      const int krs = (32 + quad * 8) ^ sx;
      bf16x8 af[4], bb[4];
#pragma unroll
      for (int mi = 0; mi < 4; mi++)
        af[mi] = *(const bf16x8*)(lb + (wm + mi * 16 + lcol) * 64 + krs);
#pragma unroll
      for (int ni = 0; ni < 4; ni++)
        bb[ni] = *(const bf16x8*)(lb + T2_A + (wn + ni * 16 + lcol) * 64 + krs);
      if (pre) {
        async_load16(srcA[3] + ko, lb2 + dA + 3 * 512);
        async_load16(srcB[0] + ko, lb2 + dB + 0 * 512);
        async_load16(srcB[1] + ko, lb2 + dB + 1 * 512);
      }
      BARRIER();
      WAIT_LGKM0();
      __builtin_amdgcn_s_setprio(1);
#pragma unroll
      for (int mi = 0; mi < 4; mi++)
#pragma unroll
        for (int ni = 0; ni < 4; ni++)
          acc[mi][ni] = __builtin_amdgcn_mfma_f32_16x16x32_bf16(af[mi], bb[ni], acc[mi][ni], 0, 0, 0);
      __builtin_amdgcn_s_setprio(0);
      if (pre) { WAIT_VM6(); } else { WAIT_VM0(); }
      BARRIER();
    }
  }

  int col0 = colBase + wn;
#pragma unroll
  for (int mi = 0; mi < 4; mi++) {
#pragma unroll
    for (int r = 0; r < 4; r++) {
      int localRow = rowTile * 256 + wm + mi * 16 + quad * 4 + r;
      if (localRow < cnt) {
        size_t prow = (size_t)off + localRow;
        float wgt = pairw[prow];
        float* yr = y + prow * H_DIM + col0;
#pragma unroll
        for (int ni = 0; ni < 4; ni++)
          yr[ni * 16 + lcol] = acc[mi][ni][r] * wgt;
      }
    }
  }
}

// ---------------- combine: out[t] = y[slot(2t)] + y[slot(2t+1)] ----------------
__global__ void combine_kernel(const float* __restrict__ y, const int* __restrict__ slotOf,
                               float* __restrict__ out) {
  int t = blockIdx.x;
  int s0 = slotOf[2 * t], s1 = slotOf[2 * t + 1];
  int c = threadIdx.x * 8;
  const float4* a = (const float4*)(y + (size_t)s0 * H_DIM + c);
  const float4* b = (const float4*)(y + (size_t)s1 * H_DIM + c);
  float4 a0 = a[0], a1 = a[1], b0 = b[0], b1 = b[1];
  float4 o0 = {a0.x + b0.x, a0.y + b0.y, a0.z + b0.z, a0.w + b0.w};
  float4 o1 = {a1.x + b1.x, a1.y + b1.y, a1.z + b1.z, a1.w + b1.w};
  float4* dst = (float4*)(out + (size_t)t * H_DIM + c);
  dst[0] = o0; dst[1] = o1;
}

extern "C" void kernel_launch(void* const* d_in, const int* in_sizes, int n_in,
                              void* d_out, int out_size, void* d_ws, size_t ws_size,
                              hipStream_t stream) {
  const float* x    = (const float*)d_in[0];
  const int*   eidx = (const int*)d_in[1];
  const float* ew   = (const float*)d_in[2];
  const float* gate = (const float*)d_in[3];
  const float* up   = (const float*)d_in[4];
  const float* down = (const float*)d_in[5];
  float* out = (float*)d_out;
  char* ws = (char*)d_ws;

  if (ws_size < WS_FULL) {
    hipMemsetAsync(d_out, 0, (size_t)NTOK * H_DIM * sizeof(float), stream);
    return;
  }

  int*      counts  = (int*)(ws + WS_COUNTS);
  int*      offsets = (int*)(ws + WS_OFFSETS);
  int*      tokid   = (int*)(ws + WS_TOKID);
  int*      slotOf  = (int*)(ws + WS_SLOT);
  float*    pairw   = (float*)(ws + WS_PAIRW);
  uint16_t* xg      = (uint16_t*)(ws + WS_XG);
  uint16_t* inter   = (uint16_t*)(ws + WS_INTER);
  float*    y       = (float*)(ws + WS_Y);
  uint16_t* gw      = (uint16_t*)(ws + WS_GW);
  uint16_t* uw      = (uint16_t*)(ws + WS_UW);
  uint16_t* dwp     = (uint16_t*)(ws + WS_DW);

  route_kernel<<<1, 256, 0, stream>>>(eidx, ew, counts, offsets, tokid, slotOf, pairw);
  gather_cast_kernel<<<NPAIR, 256, 0, stream>>>(x, tokid, xg);
  cast3_kernel<<<dim3(2048, 3), 256, 0, stream>>>(gate, up, down, gw, uw, dwp);

  gemm1_v5<<<dim3(I_DIM / 64, NPAIR / 256, NEXP), 512, 0, stream>>>(
      xg, gw, uw, counts, offsets, inter);
  gemm2_v5<<<dim3(H_DIM / 128, NPAIR / 256, NEXP), 512, 0, stream>>>(
      inter, dwp, counts, offsets, pairw, y);
  combine_kernel<<<NTOK, 256, 0, stream>>>(y, slotOf, out);
}